// Round 5
// baseline (331.528 us; speedup 1.0000x reference)
//
#include <hip/hip_runtime.h>

// RA_MLA_Attention — MI355X (gfx950). Round 4.
// B=1, T=2048, E=2048, H=16, D=128, L=64, RA_WINDOW=64, RA_ALPHA=0.5
//
// Round-4 = round-3 with the LDS-stride bug fixed:
//   * Ks/Ps rows are 64 elements (latent/s dim) — stride MUST be >=64.
//     Round 3 used 40 (data corruption). Restored to 72 (round-2-verified).
//   * Occupancy via __launch_bounds__(256,4): 4 blocks/CU x 37.4KB = 149.5KB
//     fits the 160KB LDS pool (round 2 artificially declared 3).
//   * Kept: swizzled coalesced partO stores + matching k_merge, 128x64 qkv
//     GEMM tiles, 128x128 out-proj, fused f2b x4, fused rowsums.

#define T_ 2048
#define E_ 2048
#define H_ 16
#define D_ 128
#define L_ 64
#define NQ 1152            // fused qkv GEMM N (1024 ql | 64 k | 64 v)

typedef float  floatx4 __attribute__((ext_vector_type(4)));
typedef __bf16 bf16x8  __attribute__((ext_vector_type(8)));

__device__ __forceinline__ ushort f2b(float x){           // fp32 -> bf16 bits, RNE
  unsigned int u = __float_as_uint(x);
  u = (u + 0x7fffu + ((u >> 16) & 1u)) >> 16;
  return (ushort)u;
}
__device__ __forceinline__ float blo(unsigned int u){ return __uint_as_float(u << 16); }
__device__ __forceinline__ float bhi(unsigned int u){ return __uint_as_float(u & 0xffff0000u); }

__device__ __forceinline__ void glds16(const ushort* g, ushort* l){
#if __has_builtin(__builtin_amdgcn_global_load_lds)
  __builtin_amdgcn_global_load_lds((const __attribute__((address_space(1))) void*)g,
                                   (__attribute__((address_space(3))) void*)l, 16, 0, 0);
#else
  *(uint4*)l = *(const uint4*)g;
#endif
}

// ---------------- fused fp32 -> bf16 convert (4 tensors, 1 launch) ----------
__global__ __launch_bounds__(256)
void k_f2b4(const float* __restrict__ a, ushort* __restrict__ oa,
            const float* __restrict__ b, ushort* __restrict__ ob,
            const float* __restrict__ c, ushort* __restrict__ oc,
            const float* __restrict__ d, ushort* __restrict__ od){
  int bid = blockIdx.x; const float* src; ushort* dst; int base;
  if (bid < 4096){ src=a; dst=oa; base=bid; }
  else if (bid < 8192){ src=b; dst=ob; base=bid-4096; }
  else if (bid < 8320){ src=c; dst=oc; base=bid-8192; }
  else { src=d; dst=od; base=bid-8320; }
  int i = (base*256 + (int)threadIdx.x)*4;
  float4 v = *(const float4*)(src + i);
  ushort4 o; o.x=f2b(v.x); o.y=f2b(v.y); o.z=f2b(v.z); o.w=f2b(v.w);
  *(ushort4*)(dst + i) = o;
}

// ---------------- fold q_to_latent into Wq:  Wql[(h,l),e] (rows of Wqkvb) ----
__global__ __launch_bounds__(128)
void k_prep_wql(const float* __restrict__ Wq, const float* __restrict__ q2l,
                ushort* __restrict__ Wql){
  const int h = blockIdx.z, lh = blockIdx.y;            // l half: lh*32..lh*32+31
  const int e = blockIdx.x*128 + threadIdx.x;
  const float* qb = q2l + (size_t)h*D_*L_ + lh*32;
  float acc[32];
  #pragma unroll
  for (int i=0;i<32;++i) acc[i]=0.f;
  for (int d=0; d<128; ++d){
    float wv = Wq[(size_t)(h*128+d)*E_ + e];
    #pragma unroll
    for (int i=0;i<32;++i) acc[i] += wv*qb[(size_t)d*64 + i];
  }
  #pragma unroll
  for (int i=0;i<32;++i) Wql[(size_t)(h*64 + lh*32 + i)*E_ + e] = f2b(acc[i]);
}

// ---------------- vupT[h][d][l] = vup[h][l][d], bf16 ----------------
__global__ __launch_bounds__(256)
void k_prep_vupT(const float* __restrict__ vup, ushort* __restrict__ vupT){
  const int h = blockIdx.x, tid = threadIdx.x;
  for (int idx = tid; idx < L_*D_; idx += 256){
    int l = idx >> 7, d = idx & 127;
    vupT[(size_t)h*D_*L_ + d*64 + l] = f2b(vup[(size_t)h*L_*D_ + idx]);
  }
}

// ---------------- m97-style GEMM: C[M,N] = A[M,K] @ B[N,K]^T ----------------
// 4 waves 2x2; BM=32*MT, BN=32*NT. OB16: bf16 out with col-block scale.
template<int MT,int NT,bool OB16>
__global__ __launch_bounds__(256)
void gemm_glds(const ushort* __restrict__ A, const ushort* __restrict__ B,
               float* __restrict__ Cf, ushort* __restrict__ Cb,
               int M, int N, int K, float scale){
  constexpr int BM = 32*MT, BN = 32*NT;
  constexpr int IA = BM/64, IB = BN/64;
  __shared__ ushort As[BM*32];
  __shared__ ushort Bs[BN*32];
  const int tid = threadIdx.x, lane = tid&63, wv = tid>>6;
  const int wm = wv & 1, wn = wv >> 1;
  const int l15 = lane&15, quad = lane>>4;
  const int m0 = blockIdx.y*BM, n0 = blockIdx.x*BN;
  const float sc = (n0 < 1024) ? scale : 1.0f;     // qkv: ql cols scaled
  floatx4 acc[MT][NT] = {};
  for (int k0=0; k0<K; k0+=32){
    __syncthreads();
    #pragma unroll
    for (int j=0;j<IA;++j){
      int c = (j*4 + wv)*64 + lane; int row = c>>2, kc = (c&3)*8;
      glds16(A + (size_t)(m0+row)*K + k0 + kc, &As[c*8]);
    }
    #pragma unroll
    for (int j=0;j<IB;++j){
      int c = (j*4 + wv)*64 + lane; int row = c>>2, kc = (c&3)*8;
      glds16(B + (size_t)(n0+row)*K + k0 + kc, &Bs[c*8]);
    }
    __syncthreads();
    bf16x8 af[MT], bfr[NT];
    #pragma unroll
    for (int mi=0;mi<MT;++mi)
      af[mi] = *(const bf16x8*)(&As[(wm*MT*16 + mi*16 + l15)*32 + quad*8]);
    #pragma unroll
    for (int ni=0;ni<NT;++ni)
      bfr[ni] = *(const bf16x8*)(&Bs[(wn*NT*16 + ni*16 + l15)*32 + quad*8]);
    #pragma unroll
    for (int mi=0;mi<MT;++mi)
      #pragma unroll
      for (int ni=0;ni<NT;++ni)
        acc[mi][ni] = __builtin_amdgcn_mfma_f32_16x16x32_bf16(af[mi], bfr[ni], acc[mi][ni], 0,0,0);
  }
  #pragma unroll
  for (int mi=0;mi<MT;++mi){
    const int rb = m0 + wm*MT*16 + mi*16 + quad*4;
    #pragma unroll
    for (int ni=0;ni<NT;++ni){
      const int col = n0 + wn*NT*16 + ni*16 + l15;
      #pragma unroll
      for (int r=0;r<4;++r){
        if constexpr (OB16) Cb[(size_t)(rb+r)*N + col] = f2b(acc[mi][ni][r]*sc);
        else                Cf[(size_t)(rb+r)*N + col] = acc[mi][ni][r];
      }
    }
  }
}

// ---------------- rowsums (rsq + rsk, one launch) ----------------
__global__ __launch_bounds__(256)
void k_rowsums(const ushort* __restrict__ qkvb,
               float* __restrict__ rsq, float* __restrict__ rsk){
  int i = blockIdx.x*256 + threadIdx.x;
  const ushort* src; float* dst;
  if (i < T_*H_){
    int t = i>>4, g = i&15;
    src = qkvb + (size_t)t*NQ + g*64; dst = rsq + i;
  } else {
    int t = i - T_*H_;
    if (t >= T_) return;
    src = qkvb + (size_t)t*NQ + 1024; dst = rsk + t;
  }
  const uint4* p = (const uint4*)src;
  float s = 0.f;
  #pragma unroll
  for (int j=0;j<8;++j){
    uint4 u = p[j];
    const unsigned int uu[4] = {u.x,u.y,u.z,u.w};
    #pragma unroll
    for (int q=0;q<4;++q){ s += blo(uu[q]); s += bhi(uu[q]); }
  }
  *dst = s;
}

// ---------------- V_exp^T[h][d][t] via MFMA, register-only ----------------
__global__ __launch_bounds__(256)
void k_vexp_mfma(const ushort* __restrict__ qkvb, const ushort* __restrict__ vupT,
                 ushort* __restrict__ vexpT){
  const int h = blockIdx.y, t0 = blockIdx.x*64;
  const int tid = threadIdx.x, lane = tid&63, w = tid>>6;
  const int l15 = lane&15, quad = lane>>4;
  bf16x8 a[2][2], b[4][2];
  #pragma unroll
  for (int mt=0;mt<2;++mt)
    #pragma unroll
    for (int kk=0;kk<2;++kk)
      a[mt][kk] = *(const bf16x8*)(vupT + (size_t)h*D_*L_ + (w*32+mt*16+l15)*64 + kk*32 + quad*8);
  #pragma unroll
  for (int nt=0;nt<4;++nt)
    #pragma unroll
    for (int kk=0;kk<2;++kk)
      b[nt][kk] = *(const bf16x8*)(qkvb + (size_t)(t0+nt*16+l15)*NQ + 1088 + kk*32 + quad*8);
  floatx4 acc[2][4] = {};
  #pragma unroll
  for (int mt=0;mt<2;++mt)
    #pragma unroll
    for (int nt=0;nt<4;++nt)
      #pragma unroll
      for (int kk=0;kk<2;++kk)
        acc[mt][nt] = __builtin_amdgcn_mfma_f32_16x16x32_bf16(a[mt][kk], b[nt][kk], acc[mt][nt], 0,0,0);
  #pragma unroll
  for (int mt=0;mt<2;++mt)
    #pragma unroll
    for (int nt=0;nt<4;++nt)
      #pragma unroll
      for (int r=0;r<4;++r)
        vexpT[((size_t)h*D_ + w*32+mt*16+quad*4+r)*T_ + t0 + nt*16 + l15] = f2b(acc[mt][nt][r]);
}

// ---------------- flash attention, split-S ----------------
// Block = (head, 64-row Q-tile qt, S-chunk c of CH tiles). 4 waves.
// Ks/Ps rows are 64 elements wide -> stride 72 (16B-aligned, conflict-safe).
// LDS 37.4KB; __launch_bounds__(256,4) -> 4 blocks/CU (149.5KB of 160KB).
__global__ __launch_bounds__(256, 4)
void k_attn(const ushort* __restrict__ qkvb,   // [T][1152] bf16
            const float*  __restrict__ rsq,    // [T][16]  (scaled rowsums)
            const float*  __restrict__ rsk,    // [T]
            const ushort* __restrict__ vexpT,  // [16][128][T] bf16
            ushort*       __restrict__ ctx,    // [T][2048] bf16
            ushort*       __restrict__ partO,  // [16][24][4] swizzled 64x128 bf16
            float*        __restrict__ partML, // [16][24][4][64][2]
            int CH){
  constexpr int KP = 72, VP = 72, PP = 72;
  __shared__ ushort Ks[64*KP];
  __shared__ ushort Vts[128*VP];
  __shared__ ushort Ps[4][16*PP];
  const int h  = blockIdx.y;
  const int bxr = (int)gridDim.x - 1 - (int)blockIdx.x;   // heavy tiles first
  int qt, c;
  if (CH == 8){
    if (bxr < 8){ qt = bxr; c = 0; }
    else if (bxr < 24){ int u = bxr-8;  qt = 8  + (u>>1); c = u&1; }
    else if (bxr < 48){ int u = bxr-24; qt = 16 + u/3;    c = u - (u/3)*3; }
    else               { int u = bxr-48; qt = 24 + (u>>2); c = u&3; }
  } else { qt = bxr; c = 0; }
  const int nct = (qt + CH) / CH;
  const int stBeg = c*CH, stEnd = min(qt, stBeg + CH - 1);
  const int t0 = qt*64;
  const int tid = threadIdx.x, lane = tid & 63, w = tid >> 6;
  const int l15 = lane & 15, quad = lane >> 4;

  const int qrow = t0 + w*16 + l15;
  const bf16x8 q0 = *(const bf16x8*)(qkvb + (size_t)qrow*NQ + h*64 + quad*8);
  const bf16x8 q1 = *(const bf16x8*)(qkvb + (size_t)qrow*NQ + h*64 + 32 + quad*8);
  const float rqv = rsq[(size_t)qrow*H_ + h] * 0.5f;      // already *isl*log2e

  float mrun = -INFINITY, lrun = 0.f;
  floatx4 o[8] = {};
  uint4 kreg[2], vreg[4];

  {
    const int sb = stBeg*64;
    #pragma unroll
    for (int j=0;j<2;++j){ int cc = tid + j*256;
      kreg[j] = *(const uint4*)(qkvb + (size_t)(sb + (cc>>3))*NQ + 1024 + (cc&7)*8); }
    #pragma unroll
    for (int j=0;j<4;++j){ int cc = tid + j*256;
      vreg[j] = *(const uint4*)(vexpT + ((size_t)h*128 + (cc>>3))*T_ + sb + (cc&7)*8); }
  }

  for (int st=stBeg; st<=stEnd; ++st){
    __syncthreads();                                   // A: prev compute reads done
    #pragma unroll
    for (int j=0;j<2;++j){ int cc = tid + j*256;
      *(uint4*)(&Ks[(cc>>3)*KP + (cc&7)*8]) = kreg[j]; }
    #pragma unroll
    for (int j=0;j<4;++j){ int cc = tid + j*256;
      *(uint4*)(&Vts[(cc>>3)*VP + (cc&7)*8]) = vreg[j]; }
    __syncthreads();                                   // B: stores visible
    if (st < stEnd){                                   // prefetch next tile
      const int s1 = (st+1)*64;
      #pragma unroll
      for (int j=0;j<2;++j){ int cc = tid + j*256;
        kreg[j] = *(const uint4*)(qkvb + (size_t)(s1 + (cc>>3))*NQ + 1024 + (cc&7)*8); }
      #pragma unroll
      for (int j=0;j<4;++j){ int cc = tid + j*256;
        vreg[j] = *(const uint4*)(vexpT + ((size_t)h*128 + (cc>>3))*T_ + s1 + (cc&7)*8); }
    }
    const int s0 = st*64;
    // ---- S^T = K Q^T : lane owns q=l15, s=jt*16+quad*4+r ----
    floatx4 sT[4] = {};
    #pragma unroll
    for (int jt=0;jt<4;++jt){
      bf16x8 k0f = *(const bf16x8*)(&Ks[(jt*16+l15)*KP + quad*8]);
      sT[jt] = __builtin_amdgcn_mfma_f32_16x16x32_bf16(k0f, q0, sT[jt], 0,0,0);
      bf16x8 k1f = *(const bf16x8*)(&Ks[(jt*16+l15)*KP + 32 + quad*8]);
      sT[jt] = __builtin_amdgcn_mfma_f32_16x16x32_bf16(k1f, q1, sT[jt], 0,0,0);
    }
    // ---- mask + rank-1 band (edge tiles only) + online softmax ----
    float xs[16];
    float mloc = -3.0e38f;
    if (st >= qt-1){
      #pragma unroll
      for (int jt=0;jt<4;++jt){
        const float4 rk4 = *(const float4*)(rsk + s0 + jt*16 + quad*4);  // broadcast
        #pragma unroll
        for (int r=0;r<4;++r){
          const int sg = s0 + jt*16 + quad*4 + r;
          const int dd = qrow - sg;
          float x = sT[jt][r];
          x = (dd <= 64) ? x + rqv*((const float*)&rk4)[r] : x;
          x = (dd < 0)   ? -3.0e38f : x;
          xs[jt*4+r] = x; mloc = fmaxf(mloc, x);
        }
      }
    } else {
      #pragma unroll
      for (int jt=0;jt<4;++jt)
        #pragma unroll
        for (int r=0;r<4;++r){
          float x = sT[jt][r];
          xs[jt*4+r] = x; mloc = fmaxf(mloc, x);
        }
    }
    mloc = fmaxf(mloc, __shfl_xor(mloc, 16));
    mloc = fmaxf(mloc, __shfl_xor(mloc, 32));
    const float mn = fmaxf(mrun, mloc);
    const float al = exp2f(mrun - mn);
    float pr[16];
    float ss = 0.f;
    #pragma unroll
    for (int i=0;i<16;++i){ float p = exp2f(xs[i]-mn); pr[i]=p; ss+=p; }
    ss += __shfl_xor(ss, 16); ss += __shfl_xor(ss, 32);
    lrun = lrun*al + ss; mrun = mn;
    // ---- P write (wave-private 16x72; same-wave ordering, no barrier) ----
    #pragma unroll
    for (int jt=0;jt<4;++jt){
      ushort4 pw; pw.x=f2b(pr[jt*4]); pw.y=f2b(pr[jt*4+1]);
      pw.z=f2b(pr[jt*4+2]); pw.w=f2b(pr[jt*4+3]);
      *(ushort4*)(&Ps[w][l15*PP + jt*16 + quad*4]) = pw;
    }
    // ---- rescale O rows (skip when no new max anywhere in wave) ----
    if (__any(al < 1.0f)){
      float alr[4];
      #pragma unroll
      for (int r=0;r<4;++r) alr[r] = __shfl(al, quad*4 + r);
      #pragma unroll
      for (int nt=0;nt<8;++nt){
        o[nt][0]*=alr[0]; o[nt][1]*=alr[1]; o[nt][2]*=alr[2]; o[nt][3]*=alr[3];
      }
    }
    // ---- O += P V ----
    #pragma unroll
    for (int kks=0;kks<2;++kks){
      bf16x8 pf = *(const bf16x8*)(&Ps[w][l15*PP + kks*32 + quad*8]);
      #pragma unroll
      for (int nt=0;nt<8;++nt){
        bf16x8 vf = *(const bf16x8*)(&Vts[(nt*16+l15)*VP + kks*32 + quad*8]);
        o[nt] = __builtin_amdgcn_mfma_f32_16x16x32_bf16(pf, vf, o[nt], 0,0,0);
      }
    }
  }
  // ---- epilogue ----
  const float linv = 1.f/lrun;
  float lr4[4];
  #pragma unroll
  for (int r=0;r<4;++r) lr4[r] = __shfl(linv, quad*4 + r);
  if (nct == 1){
    #pragma unroll
    for (int r=0;r<4;++r){
      const int row = t0 + w*16 + quad*4 + r;
      #pragma unroll
      for (int nt=0;nt<8;++nt)
        ctx[(size_t)row*E_ + h*D_ + nt*16 + l15] = f2b(o[nt][r]*lr4[r]);
    }
  } else {
    const int slot = (h*24 + (qt-8))*4 + c;
    ushort* po = partO + (size_t)slot*8192;            // swizzled [w][nt][r][quad*16+l15]
    #pragma unroll
    for (int nt=0;nt<8;++nt)
      #pragma unroll
      for (int r=0;r<4;++r)
        po[((w*8+nt)*4+r)*64 + quad*16 + l15] = f2b(o[nt][r]*lr4[r]);  // 128B/instr
    if (quad == 0){
      float2 ml; ml.x = mrun; ml.y = lrun;
      ((float2*)partML)[(size_t)slot*64 + w*16 + l15] = ml;
    }
  }
}

// ---------------- merge partials -> ctx (qt >= 8) ----------------
__global__ __launch_bounds__(256)
void k_merge(const ushort* __restrict__ partO, const float* __restrict__ partML,
             ushort* __restrict__ ctx){
  const int h = blockIdx.y, qt = 8 + blockIdx.x;
  const int nct = (qt + 8) / 8;
  const int tid = threadIdx.x;
  const int rg = tid >> 2, d0 = (tid & 3)*32;
  const int w = rg >> 4, quad = (rg >> 2) & 3, rr = rg & 3;
  const int n0 = d0 >> 4;
  const int sbase = (h*24 + (qt-8))*4;
  float m[4], l[4], M = -INFINITY;
  for (int c=0;c<4;++c){
    if (c < nct){
      float2 v = ((const float2*)partML)[(size_t)(sbase+c)*64 + rg];
      m[c]=v.x; l[c]=v.y; M = fmaxf(M, v.x);
    }
  }
  float lt = 0.f, wgt[4];
  for (int c=0;c<4;++c){
    if (c < nct){ wgt[c] = exp2f(m[c]-M)*l[c]; lt += wgt[c]; }
  }
  const float inv = 1.f/lt;
  float acc[32];
  #pragma unroll
  for (int i=0;i<32;++i) acc[i]=0.f;
  for (int c=0;c<4;++c){
    if (c >= nct) break;
    const float sc = wgt[c]*inv;
    const ushort* po = partO + (size_t)(sbase+c)*8192;
    #pragma unroll
    for (int nn=0;nn<2;++nn){
      const ushort* p2 = po + ((w*8 + n0+nn)*4 + rr)*64 + quad*16;
      uint4 u  = *(const uint4*)p2;
      uint4 u2 = *(const uint4*)(p2 + 8);
      const unsigned int uu[8] = {u.x,u.y,u.z,u.w,u2.x,u2.y,u2.z,u2.w};
      #pragma unroll
      for (int q=0;q<8;++q){
        acc[nn*16+q*2]   += sc*blo(uu[q]);
        acc[nn*16+q*2+1] += sc*bhi(uu[q]);
      }
    }
  }
  ushort* dst = ctx + (size_t)(qt*64 + rg)*E_ + h*D_ + d0;
  #pragma unroll
  for (int k=0;k<8;++k){
    ushort4 ov; ov.x=f2b(acc[k*4]); ov.y=f2b(acc[k*4+1]);
    ov.z=f2b(acc[k*4+2]); ov.w=f2b(acc[k*4+3]);
    *(ushort4*)(dst + k*4) = ov;
  }
}

// ---------------- launch ----------------
extern "C" void kernel_launch(void* const* d_in, const int* in_sizes, int n_in,
                              void* d_out, int out_size, void* d_ws, size_t ws_size,
                              hipStream_t stream) {
  const float* hs  = (const float*)d_in[0];
  const float* Wq  = (const float*)d_in[1];
  const float* Wk  = (const float*)d_in[2];
  const float* Wv  = (const float*)d_in[3];
  const float* q2l = (const float*)d_in[4];
  const float* vup = (const float*)d_in[5];
  const float* Wo  = (const float*)d_in[6];
  float* out = (float*)d_out;
  char* ws = (char*)d_ws;

  // workspace layout (bytes)
  ushort* hsb   = (ushort*)(ws + 0);           // [2048][2048] bf16
  ushort* Wqkvb = (ushort*)(ws + 8388608);     // [1152][2048] bf16 (ql|k|v)
  ushort* Wob   = (ushort*)(ws + 13107200);    // [2048][2048] bf16
  ushort* qkvb  = (ushort*)(ws + 21495808);    // [2048][1152] bf16
  ushort* vupT  = (ushort*)(ws + 26214400);    // [16][128][64] bf16
  float*  rsqp  = (float*) (ws + 26476544);    // [2048][16]
  float*  rskp  = (float*) (ws + 26607616);    // [2048]
  ushort* vexpT = (ushort*)(ws + 26615808);    // [16][128][2048] bf16
  ushort* ctxb  = (ushort*)(ws + 35004416);    // [2048][2048] bf16
  ushort* partO = (ushort*)(ws + 43393024);    // [16][24][4] x 8192 bf16 (swizzled)
  float*  partML= (float*) (ws + 68558848);    // [16][24][4][64][2]
  const size_t NEED = 69345280;
  const int CH = (ws_size >= NEED) ? 8 : 32;

  // 1) bf16 conversions (hs, Wo, Wk, Wv) in one launch
  k_f2b4<<<8448, 256, 0, stream>>>(hs, hsb, Wo, Wob,
                                   Wk, Wqkvb + (size_t)1024*E_,
                                   Wv, Wqkvb + (size_t)1088*E_);

  // 2) weight prep
  k_prep_wql<<<dim3(16,2,16), 128, 0, stream>>>(Wq, q2l, Wqkvb);
  k_prep_vupT<<<16, 256, 0, stream>>>(vup, vupT);

  // 3) fused q_latent|k|v GEMM -> qkvb [2048][1152] (ql cols pre-scaled)
  gemm_glds<4,2,true><<<dim3(18,16), 256, 0, stream>>>(
      hsb, Wqkvb, nullptr, qkvb, T_, NQ, E_, 0.18033688f);

  // 4) rowsums (one launch)
  k_rowsums<<<136, 256, 0, stream>>>(qkvb, rsqp, rskp);

  // 5) V_exp^T via MFMA
  k_vexp_mfma<<<dim3(32,16), 256, 0, stream>>>(qkvb, vupT, vexpT);

  // 6) flash attention (split-S) -> ctx / partials
  k_attn<<<dim3(CH==8 ? 80 : 32, 16), 256, 0, stream>>>(
      qkvb, rsqp, rskp, vexpT, ctxb, partO, partML, CH);

  // 7) merge partials
  if (CH == 8)
    k_merge<<<dim3(24,16), 256, 0, stream>>>(partO, partML, ctxb);

  // 8) out = ctx @ Wo^T  (fp32 to d_out), 128x128 tiles
  gemm_glds<4,4,false><<<dim3(16,16), 256, 0, stream>>>(
      ctxb, Wob, out, nullptr, T_, E_, E_, 1.0f);
}

// Round 6
// 300.973 us; speedup vs baseline: 1.1015x; 1.1015x over previous
//
#include <hip/hip_runtime.h>

// RA_MLA_Attention — MI355X (gfx950). Round 5.
// B=1, T=2048, E=2048, H=16, D=128, L=64, RA_WINDOW=64, RA_ALPHA=0.5
//
// Round-5 changes (attack the ~160MB of unexplained HBM writes = register
// spill to scratch from the prefetch + softmax arrays):
//   * k_attn staging via __builtin_amdgcn_global_load_lds (async, zero VGPR
//     staging state). K/V LDS strides = 64 (unpadded, contiguous in lane
//     order — required by the wave-uniform-base+lane*16 glds semantics;
//     same layout as the verified m97 GEMM pattern).
//   * softmax xs[]/pr[] arrays eliminated — band/mask/exp computed in place
//     in the sT accumulators. Live set ~75 regs -> no spill at (256,4).
//   * everything else identical to round 4 (split-S CH=8, swizzled partO,
//     k_merge, fused GEMMs).

#define T_ 2048
#define E_ 2048
#define H_ 16
#define D_ 128
#define L_ 64
#define NQ 1152            // fused qkv GEMM N (1024 ql | 64 k | 64 v)

typedef float  floatx4 __attribute__((ext_vector_type(4)));
typedef __bf16 bf16x8  __attribute__((ext_vector_type(8)));

__device__ __forceinline__ ushort f2b(float x){           // fp32 -> bf16 bits, RNE
  unsigned int u = __float_as_uint(x);
  u = (u + 0x7fffu + ((u >> 16) & 1u)) >> 16;
  return (ushort)u;
}
__device__ __forceinline__ float blo(unsigned int u){ return __uint_as_float(u << 16); }
__device__ __forceinline__ float bhi(unsigned int u){ return __uint_as_float(u & 0xffff0000u); }

__device__ __forceinline__ void glds16(const ushort* g, ushort* l){
#if __has_builtin(__builtin_amdgcn_global_load_lds)
  __builtin_amdgcn_global_load_lds((const __attribute__((address_space(1))) void*)g,
                                   (__attribute__((address_space(3))) void*)l, 16, 0, 0);
#else
  *(uint4*)l = *(const uint4*)g;
#endif
}

// ---------------- fused fp32 -> bf16 convert (4 tensors, 1 launch) ----------
__global__ __launch_bounds__(256)
void k_f2b4(const float* __restrict__ a, ushort* __restrict__ oa,
            const float* __restrict__ b, ushort* __restrict__ ob,
            const float* __restrict__ c, ushort* __restrict__ oc,
            const float* __restrict__ d, ushort* __restrict__ od){
  int bid = blockIdx.x; const float* src; ushort* dst; int base;
  if (bid < 4096){ src=a; dst=oa; base=bid; }
  else if (bid < 8192){ src=b; dst=ob; base=bid-4096; }
  else if (bid < 8320){ src=c; dst=oc; base=bid-8192; }
  else { src=d; dst=od; base=bid-8320; }
  int i = (base*256 + (int)threadIdx.x)*4;
  float4 v = *(const float4*)(src + i);
  ushort4 o; o.x=f2b(v.x); o.y=f2b(v.y); o.z=f2b(v.z); o.w=f2b(v.w);
  *(ushort4*)(dst + i) = o;
}

// ---------------- fold q_to_latent into Wq:  Wql[(h,l),e] (rows of Wqkvb) ----
__global__ __launch_bounds__(128)
void k_prep_wql(const float* __restrict__ Wq, const float* __restrict__ q2l,
                ushort* __restrict__ Wql){
  const int h = blockIdx.z, lh = blockIdx.y;            // l half: lh*32..lh*32+31
  const int e = blockIdx.x*128 + threadIdx.x;
  const float* qb = q2l + (size_t)h*D_*L_ + lh*32;
  float acc[32];
  #pragma unroll
  for (int i=0;i<32;++i) acc[i]=0.f;
  for (int d=0; d<128; ++d){
    float wv = Wq[(size_t)(h*128+d)*E_ + e];
    #pragma unroll
    for (int i=0;i<32;++i) acc[i] += wv*qb[(size_t)d*64 + i];
  }
  #pragma unroll
  for (int i=0;i<32;++i) Wql[(size_t)(h*64 + lh*32 + i)*E_ + e] = f2b(acc[i]);
}

// ---------------- vupT[h][d][l] = vup[h][l][d], bf16 ----------------
__global__ __launch_bounds__(256)
void k_prep_vupT(const float* __restrict__ vup, ushort* __restrict__ vupT){
  const int h = blockIdx.x, tid = threadIdx.x;
  for (int idx = tid; idx < L_*D_; idx += 256){
    int l = idx >> 7, d = idx & 127;
    vupT[(size_t)h*D_*L_ + d*64 + l] = f2b(vup[(size_t)h*L_*D_ + idx]);
  }
}

// ---------------- m97-style GEMM: C[M,N] = A[M,K] @ B[N,K]^T ----------------
// 4 waves 2x2; BM=32*MT, BN=32*NT. OB16: bf16 out with col-block scale.
template<int MT,int NT,bool OB16>
__global__ __launch_bounds__(256)
void gemm_glds(const ushort* __restrict__ A, const ushort* __restrict__ B,
               float* __restrict__ Cf, ushort* __restrict__ Cb,
               int M, int N, int K, float scale){
  constexpr int BM = 32*MT, BN = 32*NT;
  constexpr int IA = BM/64, IB = BN/64;
  __shared__ ushort As[BM*32];
  __shared__ ushort Bs[BN*32];
  const int tid = threadIdx.x, lane = tid&63, wv = tid>>6;
  const int wm = wv & 1, wn = wv >> 1;
  const int l15 = lane&15, quad = lane>>4;
  const int m0 = blockIdx.y*BM, n0 = blockIdx.x*BN;
  const float sc = (n0 < 1024) ? scale : 1.0f;     // qkv: ql cols scaled
  floatx4 acc[MT][NT] = {};
  for (int k0=0; k0<K; k0+=32){
    __syncthreads();
    #pragma unroll
    for (int j=0;j<IA;++j){
      int c = (j*4 + wv)*64 + lane; int row = c>>2, kc = (c&3)*8;
      glds16(A + (size_t)(m0+row)*K + k0 + kc, &As[c*8]);
    }
    #pragma unroll
    for (int j=0;j<IB;++j){
      int c = (j*4 + wv)*64 + lane; int row = c>>2, kc = (c&3)*8;
      glds16(B + (size_t)(n0+row)*K + k0 + kc, &Bs[c*8]);
    }
    __syncthreads();
    bf16x8 af[MT], bfr[NT];
    #pragma unroll
    for (int mi=0;mi<MT;++mi)
      af[mi] = *(const bf16x8*)(&As[(wm*MT*16 + mi*16 + l15)*32 + quad*8]);
    #pragma unroll
    for (int ni=0;ni<NT;++ni)
      bfr[ni] = *(const bf16x8*)(&Bs[(wn*NT*16 + ni*16 + l15)*32 + quad*8]);
    #pragma unroll
    for (int mi=0;mi<MT;++mi)
      #pragma unroll
      for (int ni=0;ni<NT;++ni)
        acc[mi][ni] = __builtin_amdgcn_mfma_f32_16x16x32_bf16(af[mi], bfr[ni], acc[mi][ni], 0,0,0);
  }
  #pragma unroll
  for (int mi=0;mi<MT;++mi){
    const int rb = m0 + wm*MT*16 + mi*16 + quad*4;
    #pragma unroll
    for (int ni=0;ni<NT;++ni){
      const int col = n0 + wn*NT*16 + ni*16 + l15;
      #pragma unroll
      for (int r=0;r<4;++r){
        if constexpr (OB16) Cb[(size_t)(rb+r)*N + col] = f2b(acc[mi][ni][r]*sc);
        else                Cf[(size_t)(rb+r)*N + col] = acc[mi][ni][r];
      }
    }
  }
}

// ---------------- rowsums (rsq + rsk, one launch) ----------------
__global__ __launch_bounds__(256)
void k_rowsums(const ushort* __restrict__ qkvb,
               float* __restrict__ rsq, float* __restrict__ rsk){
  int i = blockIdx.x*256 + threadIdx.x;
  const ushort* src; float* dst;
  if (i < T_*H_){
    int t = i>>4, g = i&15;
    src = qkvb + (size_t)t*NQ + g*64; dst = rsq + i;
  } else {
    int t = i - T_*H_;
    if (t >= T_) return;
    src = qkvb + (size_t)t*NQ + 1024; dst = rsk + t;
  }
  const uint4* p = (const uint4*)src;
  float s = 0.f;
  #pragma unroll
  for (int j=0;j<8;++j){
    uint4 u = p[j];
    const unsigned int uu[4] = {u.x,u.y,u.z,u.w};
    #pragma unroll
    for (int q=0;q<4;++q){ s += blo(uu[q]); s += bhi(uu[q]); }
  }
  *dst = s;
}

// ---------------- V_exp^T[h][d][t] via MFMA, register-only ----------------
__global__ __launch_bounds__(256)
void k_vexp_mfma(const ushort* __restrict__ qkvb, const ushort* __restrict__ vupT,
                 ushort* __restrict__ vexpT){
  const int h = blockIdx.y, t0 = blockIdx.x*64;
  const int tid = threadIdx.x, lane = tid&63, w = tid>>6;
  const int l15 = lane&15, quad = lane>>4;
  bf16x8 a[2][2], b[4][2];
  #pragma unroll
  for (int mt=0;mt<2;++mt)
    #pragma unroll
    for (int kk=0;kk<2;++kk)
      a[mt][kk] = *(const bf16x8*)(vupT + (size_t)h*D_*L_ + (w*32+mt*16+l15)*64 + kk*32 + quad*8);
  #pragma unroll
  for (int nt=0;nt<4;++nt)
    #pragma unroll
    for (int kk=0;kk<2;++kk)
      b[nt][kk] = *(const bf16x8*)(qkvb + (size_t)(t0+nt*16+l15)*NQ + 1088 + kk*32 + quad*8);
  floatx4 acc[2][4] = {};
  #pragma unroll
  for (int mt=0;mt<2;++mt)
    #pragma unroll
    for (int nt=0;nt<4;++nt)
      #pragma unroll
      for (int kk=0;kk<2;++kk)
        acc[mt][nt] = __builtin_amdgcn_mfma_f32_16x16x32_bf16(a[mt][kk], b[nt][kk], acc[mt][nt], 0,0,0);
  #pragma unroll
  for (int mt=0;mt<2;++mt)
    #pragma unroll
    for (int nt=0;nt<4;++nt)
      #pragma unroll
      for (int r=0;r<4;++r)
        vexpT[((size_t)h*D_ + w*32+mt*16+quad*4+r)*T_ + t0 + nt*16 + l15] = f2b(acc[mt][nt][r]);
}

// ---------------- flash attention, split-S, glds staging ----------------
// Block = (head, 64-row Q-tile qt, S-chunk c of CH tiles). 4 waves.
// K/V staged via global_load_lds into UNPADDED stride-64 LDS (wave-uniform
// base + lane*16 requirement). Softmax in place in sT (no spill arrays).
__global__ __launch_bounds__(256, 4)
void k_attn(const ushort* __restrict__ qkvb,   // [T][1152] bf16
            const float*  __restrict__ rsq,    // [T][16]  (scaled rowsums)
            const float*  __restrict__ rsk,    // [T]
            const ushort* __restrict__ vexpT,  // [16][128][T] bf16
            ushort*       __restrict__ ctx,    // [T][2048] bf16
            ushort*       __restrict__ partO,  // [16][24][4] swizzled 64x128 bf16
            float*        __restrict__ partML, // [16][24][4][64][2]
            int CH){
  constexpr int PP = 72;
  __shared__ ushort Ks[64*64];      // stride 64 (glds-contiguous)
  __shared__ ushort Vts[128*64];    // stride 64
  __shared__ ushort Ps[4][16*PP];   // wave-private, padded (ds_write/read only)
  const int h  = blockIdx.y;
  const int bxr = (int)gridDim.x - 1 - (int)blockIdx.x;   // heavy tiles first
  int qt, c;
  if (CH == 8){
    if (bxr < 8){ qt = bxr; c = 0; }
    else if (bxr < 24){ int u = bxr-8;  qt = 8  + (u>>1); c = u&1; }
    else if (bxr < 48){ int u = bxr-24; qt = 16 + u/3;    c = u - (u/3)*3; }
    else               { int u = bxr-48; qt = 24 + (u>>2); c = u&3; }
  } else { qt = bxr; c = 0; }
  const int nct = (qt + CH) / CH;
  const int stBeg = c*CH, stEnd = min(qt, stBeg + CH - 1);
  const int t0 = qt*64;
  const int tid = threadIdx.x, lane = tid & 63, w = tid >> 6;
  const int l15 = lane & 15, quad = lane >> 4;

  const int qrow = t0 + w*16 + l15;
  const bf16x8 q0 = *(const bf16x8*)(qkvb + (size_t)qrow*NQ + h*64 + quad*8);
  const bf16x8 q1 = *(const bf16x8*)(qkvb + (size_t)qrow*NQ + h*64 + 32 + quad*8);
  const float rqv = rsq[(size_t)qrow*H_ + h] * 0.5f;      // already *isl*log2e

  float mrun = -INFINITY, lrun = 0.f;
  floatx4 o[8] = {};

  for (int st=stBeg; st<=stEnd; ++st){
    const int s0 = st*64;
    __syncthreads();                                   // A: prev tile LDS reads done
    // ---- async stage K (64x64) + V (128x64), zero VGPR staging state ----
    #pragma unroll
    for (int j=0;j<2;++j){ int cc = tid + j*256;
      glds16(qkvb + (size_t)(s0 + (cc>>3))*NQ + 1024 + (cc&7)*8, &Ks[cc*8]); }
    #pragma unroll
    for (int j=0;j<4;++j){ int cc = tid + j*256;
      glds16(vexpT + ((size_t)h*128 + (cc>>3))*T_ + s0 + (cc&7)*8, &Vts[cc*8]); }
    __syncthreads();                                   // B: vmcnt(0) drain -> staged
    // ---- S^T = K Q^T : lane owns q=l15, s=jt*16+quad*4+r ----
    floatx4 sT[4] = {};
    #pragma unroll
    for (int jt=0;jt<4;++jt){
      bf16x8 k0f = *(const bf16x8*)(&Ks[(jt*16+l15)*64 + quad*8]);
      sT[jt] = __builtin_amdgcn_mfma_f32_16x16x32_bf16(k0f, q0, sT[jt], 0,0,0);
      bf16x8 k1f = *(const bf16x8*)(&Ks[(jt*16+l15)*64 + 32 + quad*8]);
      sT[jt] = __builtin_amdgcn_mfma_f32_16x16x32_bf16(k1f, q1, sT[jt], 0,0,0);
    }
    // ---- mask + rank-1 band (edge tiles only), in place in sT ----
    float mloc = -3.0e38f;
    if (st >= qt-1){
      #pragma unroll
      for (int jt=0;jt<4;++jt){
        const float4 rk4 = *(const float4*)(rsk + s0 + jt*16 + quad*4);  // broadcast
        #pragma unroll
        for (int r=0;r<4;++r){
          const int sg = s0 + jt*16 + quad*4 + r;
          const int dd = qrow - sg;
          float x = sT[jt][r];
          x = (dd <= 64) ? x + rqv*((const float*)&rk4)[r] : x;
          x = (dd < 0)   ? -3.0e38f : x;
          sT[jt][r] = x; mloc = fmaxf(mloc, x);
        }
      }
    } else {
      #pragma unroll
      for (int jt=0;jt<4;++jt)
        #pragma unroll
        for (int r=0;r<4;++r) mloc = fmaxf(mloc, sT[jt][r]);
    }
    mloc = fmaxf(mloc, __shfl_xor(mloc, 16));
    mloc = fmaxf(mloc, __shfl_xor(mloc, 32));
    const float mn = fmaxf(mrun, mloc);
    const float al = exp2f(mrun - mn);
    float ss = 0.f;
    #pragma unroll
    for (int jt=0;jt<4;++jt)
      #pragma unroll
      for (int r=0;r<4;++r){
        float p = exp2f(sT[jt][r]-mn); sT[jt][r] = p; ss += p;
      }
    ss += __shfl_xor(ss, 16); ss += __shfl_xor(ss, 32);
    lrun = lrun*al + ss; mrun = mn;
    // ---- P write (wave-private 16x72; same-wave ordering, no barrier) ----
    #pragma unroll
    for (int jt=0;jt<4;++jt){
      ushort4 pw; pw.x=f2b(sT[jt][0]); pw.y=f2b(sT[jt][1]);
      pw.z=f2b(sT[jt][2]); pw.w=f2b(sT[jt][3]);
      *(ushort4*)(&Ps[w][l15*PP + jt*16 + quad*4]) = pw;
    }
    // ---- rescale O rows (skip when no new max anywhere in wave) ----
    if (__any(al < 1.0f)){
      float alr[4];
      #pragma unroll
      for (int r=0;r<4;++r) alr[r] = __shfl(al, quad*4 + r);
      #pragma unroll
      for (int nt=0;nt<8;++nt){
        o[nt][0]*=alr[0]; o[nt][1]*=alr[1]; o[nt][2]*=alr[2]; o[nt][3]*=alr[3];
      }
    }
    // ---- O += P V ----
    #pragma unroll
    for (int kks=0;kks<2;++kks){
      bf16x8 pf = *(const bf16x8*)(&Ps[w][l15*PP + kks*32 + quad*8]);
      #pragma unroll
      for (int nt=0;nt<8;++nt){
        bf16x8 vf = *(const bf16x8*)(&Vts[(nt*16+l15)*64 + kks*32 + quad*8]);
        o[nt] = __builtin_amdgcn_mfma_f32_16x16x32_bf16(pf, vf, o[nt], 0,0,0);
      }
    }
  }
  // ---- epilogue ----
  const float linv = 1.f/lrun;
  float lr4[4];
  #pragma unroll
  for (int r=0;r<4;++r) lr4[r] = __shfl(linv, quad*4 + r);
  if (nct == 1){
    #pragma unroll
    for (int r=0;r<4;++r){
      const int row = t0 + w*16 + quad*4 + r;
      #pragma unroll
      for (int nt=0;nt<8;++nt)
        ctx[(size_t)row*E_ + h*D_ + nt*16 + l15] = f2b(o[nt][r]*lr4[r]);
    }
  } else {
    const int slot = (h*24 + (qt-8))*4 + c;
    ushort* po = partO + (size_t)slot*8192;            // swizzled [w][nt][r][lane]
    #pragma unroll
    for (int nt=0;nt<8;++nt)
      #pragma unroll
      for (int r=0;r<4;++r)
        po[((w*8+nt)*4+r)*64 + quad*16 + l15] = f2b(o[nt][r]*lr4[r]);  // 128B/instr
    if (quad == 0){
      float2 ml; ml.x = mrun; ml.y = lrun;
      ((float2*)partML)[(size_t)slot*64 + w*16 + l15] = ml;
    }
  }
}

// ---------------- merge partials -> ctx (qt >= 8) ----------------
__global__ __launch_bounds__(256)
void k_merge(const ushort* __restrict__ partO, const float* __restrict__ partML,
             ushort* __restrict__ ctx){
  const int h = blockIdx.y, qt = 8 + blockIdx.x;
  const int nct = (qt + 8) / 8;
  const int tid = threadIdx.x;
  const int rg = tid >> 2, d0 = (tid & 3)*32;
  const int w = rg >> 4, quad = (rg >> 2) & 3, rr = rg & 3;
  const int n0 = d0 >> 4;
  const int sbase = (h*24 + (qt-8))*4;
  float m[4], l[4], M = -INFINITY;
  for (int c=0;c<4;++c){
    if (c < nct){
      float2 v = ((const float2*)partML)[(size_t)(sbase+c)*64 + rg];
      m[c]=v.x; l[c]=v.y; M = fmaxf(M, v.x);
    }
  }
  float lt = 0.f, wgt[4];
  for (int c=0;c<4;++c){
    if (c < nct){ wgt[c] = exp2f(m[c]-M)*l[c]; lt += wgt[c]; }
  }
  const float inv = 1.f/lt;
  float acc[32];
  #pragma unroll
  for (int i=0;i<32;++i) acc[i]=0.f;
  for (int c=0;c<4;++c){
    if (c >= nct) break;
    const float sc = wgt[c]*inv;
    const ushort* po = partO + (size_t)(sbase+c)*8192;
    #pragma unroll
    for (int nn=0;nn<2;++nn){
      const ushort* p2 = po + ((w*8 + n0+nn)*4 + rr)*64 + quad*16;
      uint4 u  = *(const uint4*)p2;
      uint4 u2 = *(const uint4*)(p2 + 8);
      const unsigned int uu[8] = {u.x,u.y,u.z,u.w,u2.x,u2.y,u2.z,u2.w};
      #pragma unroll
      for (int q=0;q<8;++q){
        acc[nn*16+q*2]   += sc*blo(uu[q]);
        acc[nn*16+q*2+1] += sc*bhi(uu[q]);
      }
    }
  }
  ushort* dst = ctx + (size_t)(qt*64 + rg)*E_ + h*D_ + d0;
  #pragma unroll
  for (int k=0;k<8;++k){
    ushort4 ov; ov.x=f2b(acc[k*4]); ov.y=f2b(acc[k*4+1]);
    ov.z=f2b(acc[k*4+2]); ov.w=f2b(acc[k*4+3]);
    *(ushort4*)(dst + k*4) = ov;
  }
}

// ---------------- launch ----------------
extern "C" void kernel_launch(void* const* d_in, const int* in_sizes, int n_in,
                              void* d_out, int out_size, void* d_ws, size_t ws_size,
                              hipStream_t stream) {
  const float* hs  = (const float*)d_in[0];
  const float* Wq  = (const float*)d_in[1];
  const float* Wk  = (const float*)d_in[2];
  const float* Wv  = (const float*)d_in[3];
  const float* q2l = (const float*)d_in[4];
  const float* vup = (const float*)d_in[5];
  const float* Wo  = (const float*)d_in[6];
  float* out = (float*)d_out;
  char* ws = (char*)d_ws;

  // workspace layout (bytes)
  ushort* hsb   = (ushort*)(ws + 0);           // [2048][2048] bf16
  ushort* Wqkvb = (ushort*)(ws + 8388608);     // [1152][2048] bf16 (ql|k|v)
  ushort* Wob   = (ushort*)(ws + 13107200);    // [2048][2048] bf16
  ushort* qkvb  = (ushort*)(ws + 21495808);    // [2048][1152] bf16
  ushort* vupT  = (ushort*)(ws + 26214400);    // [16][128][64] bf16
  float*  rsqp  = (float*) (ws + 26476544);    // [2048][16]
  float*  rskp  = (float*) (ws + 26607616);    // [2048]
  ushort* vexpT = (ushort*)(ws + 26615808);    // [16][128][2048] bf16
  ushort* ctxb  = (ushort*)(ws + 35004416);    // [2048][2048] bf16
  ushort* partO = (ushort*)(ws + 43393024);    // [16][24][4] x 8192 bf16 (swizzled)
  float*  partML= (float*) (ws + 68558848);    // [16][24][4][64][2]
  const size_t NEED = 69345280;
  const int CH = (ws_size >= NEED) ? 8 : 32;

  // 1) bf16 conversions (hs, Wo, Wk, Wv) in one launch
  k_f2b4<<<8448, 256, 0, stream>>>(hs, hsb, Wo, Wob,
                                   Wk, Wqkvb + (size_t)1024*E_,
                                   Wv, Wqkvb + (size_t)1088*E_);

  // 2) weight prep
  k_prep_wql<<<dim3(16,2,16), 128, 0, stream>>>(Wq, q2l, Wqkvb);
  k_prep_vupT<<<16, 256, 0, stream>>>(vup, vupT);

  // 3) fused q_latent|k|v GEMM -> qkvb [2048][1152] (ql cols pre-scaled)
  gemm_glds<4,2,true><<<dim3(18,16), 256, 0, stream>>>(
      hsb, Wqkvb, nullptr, qkvb, T_, NQ, E_, 0.18033688f);

  // 4) rowsums (one launch)
  k_rowsums<<<136, 256, 0, stream>>>(qkvb, rsqp, rskp);

  // 5) V_exp^T via MFMA
  k_vexp_mfma<<<dim3(32,16), 256, 0, stream>>>(qkvb, vupT, vexpT);

  // 6) flash attention (split-S) -> ctx / partials
  k_attn<<<dim3(CH==8 ? 80 : 32, 16), 256, 0, stream>>>(
      qkvb, rsqp, rskp, vexpT, ctxb, partO, partML, CH);

  // 7) merge partials
  if (CH == 8)
    k_merge<<<dim3(24,16), 256, 0, stream>>>(partO, partML, ctxb);

  // 8) out = ctx @ Wo^T  (fp32 to d_out), 128x128 tiles
  gemm_glds<4,4,false><<<dim3(16,16), 256, 0, stream>>>(
      ctxb, Wob, out, nullptr, T_, E_, E_, 1.0f);
}

// Round 7
// 270.170 us; speedup vs baseline: 1.2271x; 1.1140x over previous
//
#include <hip/hip_runtime.h>

// RA_MLA_Attention — MI355X (gfx950). Round 6.
// B=1, T=2048, E=2048, H=16, D=128, L=64, RA_WINDOW=64, RA_ALPHA=0.5
//
// Round-6 changes:
//   * k_attn K/V LDS XOR-swizzle via glds fetch permutation (glds writes are
//     fixed at base+lane*16, but the SOURCE chunk is free): LDS chunk cc
//     holds global chunk (row, (cc&7)^(row&7)); reads index chunk^(row&7).
//     Bank-groups perfectly balanced -> kills the 10.5M conflict cycles
//     (~30% of k_attn) introduced by unpadded stride-64 rows.
//   * out-proj GEMM 64x128 tiles (512 blocks, 2/CU; was 256 = 1/CU).
//   * qkv GEMM 64x64 tiles (576 blocks, 2.25/CU).

#define T_ 2048
#define E_ 2048
#define H_ 16
#define D_ 128
#define L_ 64
#define NQ 1152            // fused qkv GEMM N (1024 ql | 64 k | 64 v)

typedef float  floatx4 __attribute__((ext_vector_type(4)));
typedef __bf16 bf16x8  __attribute__((ext_vector_type(8)));

__device__ __forceinline__ ushort f2b(float x){           // fp32 -> bf16 bits, RNE
  unsigned int u = __float_as_uint(x);
  u = (u + 0x7fffu + ((u >> 16) & 1u)) >> 16;
  return (ushort)u;
}
__device__ __forceinline__ float blo(unsigned int u){ return __uint_as_float(u << 16); }
__device__ __forceinline__ float bhi(unsigned int u){ return __uint_as_float(u & 0xffff0000u); }

__device__ __forceinline__ void glds16(const ushort* g, ushort* l){
#if __has_builtin(__builtin_amdgcn_global_load_lds)
  __builtin_amdgcn_global_load_lds((const __attribute__((address_space(1))) void*)g,
                                   (__attribute__((address_space(3))) void*)l, 16, 0, 0);
#else
  *(uint4*)l = *(const uint4*)g;
#endif
}

// ---------------- fused fp32 -> bf16 convert (4 tensors, 1 launch) ----------
__global__ __launch_bounds__(256)
void k_f2b4(const float* __restrict__ a, ushort* __restrict__ oa,
            const float* __restrict__ b, ushort* __restrict__ ob,
            const float* __restrict__ c, ushort* __restrict__ oc,
            const float* __restrict__ d, ushort* __restrict__ od){
  int bid = blockIdx.x; const float* src; ushort* dst; int base;
  if (bid < 4096){ src=a; dst=oa; base=bid; }
  else if (bid < 8192){ src=b; dst=ob; base=bid-4096; }
  else if (bid < 8320){ src=c; dst=oc; base=bid-8192; }
  else { src=d; dst=od; base=bid-8320; }
  int i = (base*256 + (int)threadIdx.x)*4;
  float4 v = *(const float4*)(src + i);
  ushort4 o; o.x=f2b(v.x); o.y=f2b(v.y); o.z=f2b(v.z); o.w=f2b(v.w);
  *(ushort4*)(dst + i) = o;
}

// ---------------- fold q_to_latent into Wq:  Wql[(h,l),e] (rows of Wqkvb) ----
__global__ __launch_bounds__(128)
void k_prep_wql(const float* __restrict__ Wq, const float* __restrict__ q2l,
                ushort* __restrict__ Wql){
  const int h = blockIdx.z, lh = blockIdx.y;            // l half: lh*32..lh*32+31
  const int e = blockIdx.x*128 + threadIdx.x;
  const float* qb = q2l + (size_t)h*D_*L_ + lh*32;
  float acc[32];
  #pragma unroll
  for (int i=0;i<32;++i) acc[i]=0.f;
  for (int d=0; d<128; ++d){
    float wv = Wq[(size_t)(h*128+d)*E_ + e];
    #pragma unroll
    for (int i=0;i<32;++i) acc[i] += wv*qb[(size_t)d*64 + i];
  }
  #pragma unroll
  for (int i=0;i<32;++i) Wql[(size_t)(h*64 + lh*32 + i)*E_ + e] = f2b(acc[i]);
}

// ---------------- vupT[h][d][l] = vup[h][l][d], bf16 ----------------
__global__ __launch_bounds__(256)
void k_prep_vupT(const float* __restrict__ vup, ushort* __restrict__ vupT){
  const int h = blockIdx.x, tid = threadIdx.x;
  for (int idx = tid; idx < L_*D_; idx += 256){
    int l = idx >> 7, d = idx & 127;
    vupT[(size_t)h*D_*L_ + d*64 + l] = f2b(vup[(size_t)h*L_*D_ + idx]);
  }
}

// ---------------- m97-style GEMM: C[M,N] = A[M,K] @ B[N,K]^T ----------------
// 4 waves 2x2; BM=32*MT, BN=32*NT. OB16: bf16 out with col-block scale.
template<int MT,int NT,bool OB16>
__global__ __launch_bounds__(256)
void gemm_glds(const ushort* __restrict__ A, const ushort* __restrict__ B,
               float* __restrict__ Cf, ushort* __restrict__ Cb,
               int M, int N, int K, float scale){
  constexpr int BM = 32*MT, BN = 32*NT;
  constexpr int IA = BM/64, IB = BN/64;
  __shared__ ushort As[BM*32];
  __shared__ ushort Bs[BN*32];
  const int tid = threadIdx.x, lane = tid&63, wv = tid>>6;
  const int wm = wv & 1, wn = wv >> 1;
  const int l15 = lane&15, quad = lane>>4;
  const int m0 = blockIdx.y*BM, n0 = blockIdx.x*BN;
  const float sc = (n0 < 1024) ? scale : 1.0f;     // qkv: ql cols scaled
  floatx4 acc[MT][NT] = {};
  for (int k0=0; k0<K; k0+=32){
    __syncthreads();
    #pragma unroll
    for (int j=0;j<IA;++j){
      int c = (j*4 + wv)*64 + lane; int row = c>>2, kc = (c&3)*8;
      glds16(A + (size_t)(m0+row)*K + k0 + kc, &As[c*8]);
    }
    #pragma unroll
    for (int j=0;j<IB;++j){
      int c = (j*4 + wv)*64 + lane; int row = c>>2, kc = (c&3)*8;
      glds16(B + (size_t)(n0+row)*K + k0 + kc, &Bs[c*8]);
    }
    __syncthreads();
    bf16x8 af[MT], bfr[NT];
    #pragma unroll
    for (int mi=0;mi<MT;++mi)
      af[mi] = *(const bf16x8*)(&As[(wm*MT*16 + mi*16 + l15)*32 + quad*8]);
    #pragma unroll
    for (int ni=0;ni<NT;++ni)
      bfr[ni] = *(const bf16x8*)(&Bs[(wn*NT*16 + ni*16 + l15)*32 + quad*8]);
    #pragma unroll
    for (int mi=0;mi<MT;++mi)
      #pragma unroll
      for (int ni=0;ni<NT;++ni)
        acc[mi][ni] = __builtin_amdgcn_mfma_f32_16x16x32_bf16(af[mi], bfr[ni], acc[mi][ni], 0,0,0);
  }
  #pragma unroll
  for (int mi=0;mi<MT;++mi){
    const int rb = m0 + wm*MT*16 + mi*16 + quad*4;
    #pragma unroll
    for (int ni=0;ni<NT;++ni){
      const int col = n0 + wn*NT*16 + ni*16 + l15;
      #pragma unroll
      for (int r=0;r<4;++r){
        if constexpr (OB16) Cb[(size_t)(rb+r)*N + col] = f2b(acc[mi][ni][r]*sc);
        else                Cf[(size_t)(rb+r)*N + col] = acc[mi][ni][r];
      }
    }
  }
}

// ---------------- rowsums (rsq + rsk, one launch) ----------------
__global__ __launch_bounds__(256)
void k_rowsums(const ushort* __restrict__ qkvb,
               float* __restrict__ rsq, float* __restrict__ rsk){
  int i = blockIdx.x*256 + threadIdx.x;
  const ushort* src; float* dst;
  if (i < T_*H_){
    int t = i>>4, g = i&15;
    src = qkvb + (size_t)t*NQ + g*64; dst = rsq + i;
  } else {
    int t = i - T_*H_;
    if (t >= T_) return;
    src = qkvb + (size_t)t*NQ + 1024; dst = rsk + t;
  }
  const uint4* p = (const uint4*)src;
  float s = 0.f;
  #pragma unroll
  for (int j=0;j<8;++j){
    uint4 u = p[j];
    const unsigned int uu[4] = {u.x,u.y,u.z,u.w};
    #pragma unroll
    for (int q=0;q<4;++q){ s += blo(uu[q]); s += bhi(uu[q]); }
  }
  *dst = s;
}

// ---------------- V_exp^T[h][d][t] via MFMA, register-only ----------------
__global__ __launch_bounds__(256)
void k_vexp_mfma(const ushort* __restrict__ qkvb, const ushort* __restrict__ vupT,
                 ushort* __restrict__ vexpT){
  const int h = blockIdx.y, t0 = blockIdx.x*64;
  const int tid = threadIdx.x, lane = tid&63, w = tid>>6;
  const int l15 = lane&15, quad = lane>>4;
  bf16x8 a[2][2], b[4][2];
  #pragma unroll
  for (int mt=0;mt<2;++mt)
    #pragma unroll
    for (int kk=0;kk<2;++kk)
      a[mt][kk] = *(const bf16x8*)(vupT + (size_t)h*D_*L_ + (w*32+mt*16+l15)*64 + kk*32 + quad*8);
  #pragma unroll
  for (int nt=0;nt<4;++nt)
    #pragma unroll
    for (int kk=0;kk<2;++kk)
      b[nt][kk] = *(const bf16x8*)(qkvb + (size_t)(t0+nt*16+l15)*NQ + 1088 + kk*32 + quad*8);
  floatx4 acc[2][4] = {};
  #pragma unroll
  for (int mt=0;mt<2;++mt)
    #pragma unroll
    for (int nt=0;nt<4;++nt)
      #pragma unroll
      for (int kk=0;kk<2;++kk)
        acc[mt][nt] = __builtin_amdgcn_mfma_f32_16x16x32_bf16(a[mt][kk], b[nt][kk], acc[mt][nt], 0,0,0);
  #pragma unroll
  for (int mt=0;mt<2;++mt)
    #pragma unroll
    for (int nt=0;nt<4;++nt)
      #pragma unroll
      for (int r=0;r<4;++r)
        vexpT[((size_t)h*D_ + w*32+mt*16+quad*4+r)*T_ + t0 + nt*16 + l15] = f2b(acc[mt][nt][r]);
}

// ---------------- flash attention, split-S, glds staging, XOR swizzle ------
// Block = (head, 64-row Q-tile qt, S-chunk c of CH tiles). 4 waves.
// K/V LDS: row-major stride 64, 16B chunk c of row r stored at slot c^(r&7)
// (implemented by permuting the glds SOURCE address; writes stay contiguous).
__global__ __launch_bounds__(256, 4)
void k_attn(const ushort* __restrict__ qkvb,   // [T][1152] bf16
            const float*  __restrict__ rsq,    // [T][16]  (scaled rowsums)
            const float*  __restrict__ rsk,    // [T]
            const ushort* __restrict__ vexpT,  // [16][128][T] bf16
            ushort*       __restrict__ ctx,    // [T][2048] bf16
            ushort*       __restrict__ partO,  // [16][24][4] swizzled 64x128 bf16
            float*        __restrict__ partML, // [16][24][4][64][2]
            int CH){
  constexpr int PP = 72;
  __shared__ ushort Ks[64*64];      // stride 64, XOR-swizzled chunks
  __shared__ ushort Vts[128*64];    // stride 64, XOR-swizzled chunks
  __shared__ ushort Ps[4][16*PP];   // wave-private, padded
  const int h  = blockIdx.y;
  const int bxr = (int)gridDim.x - 1 - (int)blockIdx.x;   // heavy tiles first
  int qt, c;
  if (CH == 8){
    if (bxr < 8){ qt = bxr; c = 0; }
    else if (bxr < 24){ int u = bxr-8;  qt = 8  + (u>>1); c = u&1; }
    else if (bxr < 48){ int u = bxr-24; qt = 16 + u/3;    c = u - (u/3)*3; }
    else               { int u = bxr-48; qt = 24 + (u>>2); c = u&3; }
  } else { qt = bxr; c = 0; }
  const int nct = (qt + CH) / CH;
  const int stBeg = c*CH, stEnd = min(qt, stBeg + CH - 1);
  const int t0 = qt*64;
  const int tid = threadIdx.x, lane = tid & 63, w = tid >> 6;
  const int l15 = lane & 15, quad = lane >> 4;

  const int qrow = t0 + w*16 + l15;
  const bf16x8 q0 = *(const bf16x8*)(qkvb + (size_t)qrow*NQ + h*64 + quad*8);
  const bf16x8 q1 = *(const bf16x8*)(qkvb + (size_t)qrow*NQ + h*64 + 32 + quad*8);
  const float rqv = rsq[(size_t)qrow*H_ + h] * 0.5f;      // already *isl*log2e

  float mrun = -INFINITY, lrun = 0.f;
  floatx4 o[8] = {};

  for (int st=stBeg; st<=stEnd; ++st){
    const int s0 = st*64;
    __syncthreads();                                   // A: prev tile LDS reads done
    // ---- async stage K (64x64) + V (128x64), source-permuted (XOR swizzle) ----
    #pragma unroll
    for (int j=0;j<2;++j){ int cc = tid + j*256;
      int row = cc>>3, kc = ((cc&7) ^ (row&7))*8;
      glds16(qkvb + (size_t)(s0 + row)*NQ + 1024 + kc, &Ks[cc*8]); }
    #pragma unroll
    for (int j=0;j<4;++j){ int cc = tid + j*256;
      int row = cc>>3, sc2 = ((cc&7) ^ (row&7))*8;
      glds16(vexpT + ((size_t)h*128 + row)*T_ + s0 + sc2, &Vts[cc*8]); }
    __syncthreads();                                   // B: vmcnt(0) drain -> staged
    // ---- S^T = K Q^T : lane owns q=l15, s=jt*16+quad*4+r ----
    floatx4 sT[4] = {};
    #pragma unroll
    for (int jt=0;jt<4;++jt){
      const int srow = jt*16 + l15, sx = srow & 7;
      bf16x8 k0f = *(const bf16x8*)(&Ks[srow*64 + (quad^sx)*8]);
      sT[jt] = __builtin_amdgcn_mfma_f32_16x16x32_bf16(k0f, q0, sT[jt], 0,0,0);
      bf16x8 k1f = *(const bf16x8*)(&Ks[srow*64 + ((4+quad)^sx)*8]);
      sT[jt] = __builtin_amdgcn_mfma_f32_16x16x32_bf16(k1f, q1, sT[jt], 0,0,0);
    }
    // ---- mask + rank-1 band (edge tiles only), in place in sT ----
    float mloc = -3.0e38f;
    if (st >= qt-1){
      #pragma unroll
      for (int jt=0;jt<4;++jt){
        const float4 rk4 = *(const float4*)(rsk + s0 + jt*16 + quad*4);  // broadcast
        #pragma unroll
        for (int r=0;r<4;++r){
          const int sg = s0 + jt*16 + quad*4 + r;
          const int dd = qrow - sg;
          float x = sT[jt][r];
          x = (dd <= 64) ? x + rqv*((const float*)&rk4)[r] : x;
          x = (dd < 0)   ? -3.0e38f : x;
          sT[jt][r] = x; mloc = fmaxf(mloc, x);
        }
      }
    } else {
      #pragma unroll
      for (int jt=0;jt<4;++jt)
        #pragma unroll
        for (int r=0;r<4;++r) mloc = fmaxf(mloc, sT[jt][r]);
    }
    mloc = fmaxf(mloc, __shfl_xor(mloc, 16));
    mloc = fmaxf(mloc, __shfl_xor(mloc, 32));
    const float mn = fmaxf(mrun, mloc);
    const float al = exp2f(mrun - mn);
    float ss = 0.f;
    #pragma unroll
    for (int jt=0;jt<4;++jt)
      #pragma unroll
      for (int r=0;r<4;++r){
        float p = exp2f(sT[jt][r]-mn); sT[jt][r] = p; ss += p;
      }
    ss += __shfl_xor(ss, 16); ss += __shfl_xor(ss, 32);
    lrun = lrun*al + ss; mrun = mn;
    // ---- P write (wave-private 16x72; same-wave ordering, no barrier) ----
    #pragma unroll
    for (int jt=0;jt<4;++jt){
      ushort4 pw; pw.x=f2b(sT[jt][0]); pw.y=f2b(sT[jt][1]);
      pw.z=f2b(sT[jt][2]); pw.w=f2b(sT[jt][3]);
      *(ushort4*)(&Ps[w][l15*PP + jt*16 + quad*4]) = pw;
    }
    // ---- rescale O rows (skip when no new max anywhere in wave) ----
    if (__any(al < 1.0f)){
      float alr[4];
      #pragma unroll
      for (int r=0;r<4;++r) alr[r] = __shfl(al, quad*4 + r);
      #pragma unroll
      for (int nt=0;nt<8;++nt){
        o[nt][0]*=alr[0]; o[nt][1]*=alr[1]; o[nt][2]*=alr[2]; o[nt][3]*=alr[3];
      }
    }
    // ---- O += P V ----
    #pragma unroll
    for (int kks=0;kks<2;++kks){
      bf16x8 pf = *(const bf16x8*)(&Ps[w][l15*PP + kks*32 + quad*8]);
      #pragma unroll
      for (int nt=0;nt<8;++nt){
        const int vrow = nt*16 + l15, vx = vrow & 7;
        bf16x8 vf = *(const bf16x8*)(&Vts[vrow*64 + ((kks*4+quad)^vx)*8]);
        o[nt] = __builtin_amdgcn_mfma_f32_16x16x32_bf16(pf, vf, o[nt], 0,0,0);
      }
    }
  }
  // ---- epilogue ----
  const float linv = 1.f/lrun;
  float lr4[4];
  #pragma unroll
  for (int r=0;r<4;++r) lr4[r] = __shfl(linv, quad*4 + r);
  if (nct == 1){
    #pragma unroll
    for (int r=0;r<4;++r){
      const int row = t0 + w*16 + quad*4 + r;
      #pragma unroll
      for (int nt=0;nt<8;++nt)
        ctx[(size_t)row*E_ + h*D_ + nt*16 + l15] = f2b(o[nt][r]*lr4[r]);
    }
  } else {
    const int slot = (h*24 + (qt-8))*4 + c;
    ushort* po = partO + (size_t)slot*8192;            // swizzled [w][nt][r][lane]
    #pragma unroll
    for (int nt=0;nt<8;++nt)
      #pragma unroll
      for (int r=0;r<4;++r)
        po[((w*8+nt)*4+r)*64 + quad*16 + l15] = f2b(o[nt][r]*lr4[r]);  // 128B/instr
    if (quad == 0){
      float2 ml; ml.x = mrun; ml.y = lrun;
      ((float2*)partML)[(size_t)slot*64 + w*16 + l15] = ml;
    }
  }
}

// ---------------- merge partials -> ctx (qt >= 8) ----------------
__global__ __launch_bounds__(256)
void k_merge(const ushort* __restrict__ partO, const float* __restrict__ partML,
             ushort* __restrict__ ctx){
  const int h = blockIdx.y, qt = 8 + blockIdx.x;
  const int nct = (qt + 8) / 8;
  const int tid = threadIdx.x;
  const int rg = tid >> 2, d0 = (tid & 3)*32;
  const int w = rg >> 4, quad = (rg >> 2) & 3, rr = rg & 3;
  const int n0 = d0 >> 4;
  const int sbase = (h*24 + (qt-8))*4;
  float m[4], l[4], M = -INFINITY;
  for (int c=0;c<4;++c){
    if (c < nct){
      float2 v = ((const float2*)partML)[(size_t)(sbase+c)*64 + rg];
      m[c]=v.x; l[c]=v.y; M = fmaxf(M, v.x);
    }
  }
  float lt = 0.f, wgt[4];
  for (int c=0;c<4;++c){
    if (c < nct){ wgt[c] = exp2f(m[c]-M)*l[c]; lt += wgt[c]; }
  }
  const float inv = 1.f/lt;
  float acc[32];
  #pragma unroll
  for (int i=0;i<32;++i) acc[i]=0.f;
  for (int c=0;c<4;++c){
    if (c >= nct) break;
    const float sc = wgt[c]*inv;
    const ushort* po = partO + (size_t)(sbase+c)*8192;
    #pragma unroll
    for (int nn=0;nn<2;++nn){
      const ushort* p2 = po + ((w*8 + n0+nn)*4 + rr)*64 + quad*16;
      uint4 u  = *(const uint4*)p2;
      uint4 u2 = *(const uint4*)(p2 + 8);
      const unsigned int uu[8] = {u.x,u.y,u.z,u.w,u2.x,u2.y,u2.z,u2.w};
      #pragma unroll
      for (int q=0;q<8;++q){
        acc[nn*16+q*2]   += sc*blo(uu[q]);
        acc[nn*16+q*2+1] += sc*bhi(uu[q]);
      }
    }
  }
  ushort* dst = ctx + (size_t)(qt*64 + rg)*E_ + h*D_ + d0;
  #pragma unroll
  for (int k=0;k<8;++k){
    ushort4 ov; ov.x=f2b(acc[k*4]); ov.y=f2b(acc[k*4+1]);
    ov.z=f2b(acc[k*4+2]); ov.w=f2b(acc[k*4+3]);
    *(ushort4*)(dst + k*4) = ov;
  }
}

// ---------------- launch ----------------
extern "C" void kernel_launch(void* const* d_in, const int* in_sizes, int n_in,
                              void* d_out, int out_size, void* d_ws, size_t ws_size,
                              hipStream_t stream) {
  const float* hs  = (const float*)d_in[0];
  const float* Wq  = (const float*)d_in[1];
  const float* Wk  = (const float*)d_in[2];
  const float* Wv  = (const float*)d_in[3];
  const float* q2l = (const float*)d_in[4];
  const float* vup = (const float*)d_in[5];
  const float* Wo  = (const float*)d_in[6];
  float* out = (float*)d_out;
  char* ws = (char*)d_ws;

  // workspace layout (bytes)
  ushort* hsb   = (ushort*)(ws + 0);           // [2048][2048] bf16
  ushort* Wqkvb = (ushort*)(ws + 8388608);     // [1152][2048] bf16 (ql|k|v)
  ushort* Wob   = (ushort*)(ws + 13107200);    // [2048][2048] bf16
  ushort* qkvb  = (ushort*)(ws + 21495808);    // [2048][1152] bf16
  ushort* vupT  = (ushort*)(ws + 26214400);    // [16][128][64] bf16
  float*  rsqp  = (float*) (ws + 26476544);    // [2048][16]
  float*  rskp  = (float*) (ws + 26607616);    // [2048]
  ushort* vexpT = (ushort*)(ws + 26615808);    // [16][128][2048] bf16
  ushort* ctxb  = (ushort*)(ws + 35004416);    // [2048][2048] bf16
  ushort* partO = (ushort*)(ws + 43393024);    // [16][24][4] x 8192 bf16 (swizzled)
  float*  partML= (float*) (ws + 68558848);    // [16][24][4][64][2]
  const size_t NEED = 69345280;
  const int CH = (ws_size >= NEED) ? 8 : 32;

  // 1) bf16 conversions (hs, Wo, Wk, Wv) in one launch
  k_f2b4<<<8448, 256, 0, stream>>>(hs, hsb, Wo, Wob,
                                   Wk, Wqkvb + (size_t)1024*E_,
                                   Wv, Wqkvb + (size_t)1088*E_);

  // 2) weight prep
  k_prep_wql<<<dim3(16,2,16), 128, 0, stream>>>(Wq, q2l, Wqkvb);
  k_prep_vupT<<<16, 256, 0, stream>>>(vup, vupT);

  // 3) fused q_latent|k|v GEMM -> qkvb [2048][1152] (ql cols pre-scaled)
  //    64x64 tiles: 576 blocks (2.25/CU) for latency hiding
  gemm_glds<2,2,true><<<dim3(18,32), 256, 0, stream>>>(
      hsb, Wqkvb, nullptr, qkvb, T_, NQ, E_, 0.18033688f);

  // 4) rowsums (one launch)
  k_rowsums<<<136, 256, 0, stream>>>(qkvb, rsqp, rskp);

  // 5) V_exp^T via MFMA
  k_vexp_mfma<<<dim3(32,16), 256, 0, stream>>>(qkvb, vupT, vexpT);

  // 6) flash attention (split-S) -> ctx / partials
  k_attn<<<dim3(CH==8 ? 80 : 32, 16), 256, 0, stream>>>(
      qkvb, rsqp, rskp, vexpT, ctxb, partO, partML, CH);

  // 7) merge partials
  if (CH == 8)
    k_merge<<<dim3(24,16), 256, 0, stream>>>(partO, partML, ctxb);

  // 8) out = ctx @ Wo^T (fp32 to d_out): 64x128 tiles, 512 blocks (2/CU)
  gemm_glds<2,4,false><<<dim3(16,32), 256, 0, stream>>>(
      ctxb, Wob, out, nullptr, T_, E_, E_, 1.0f);
}